// Round 6
// baseline (13343.651 us; speedup 1.0000x reference)
//
#include <hip/hip_runtime.h>

// MACRO_VRNN R6: per-step launches, NB=4, grid=640, but NT=512 (8 waves/block)
// with 8-way k-split: per-thread ratio 400 FMA : 50 mem-instr, and 4 waves/SIMD
// resident (2 blocks/CU) to hide L2 weight latency. f32 throughout (bf16 would
// flip Gumbel argmaxes). Keeps LDS union (~17KB) + fused 2-pass GRUs.

#define T_STEPS 63
#define BATCH   512
#define NA      5
#define YDIM    10
#define ZDIM    16
#define XDIM    2
#define HD      200
#define MDIM    90
#define HM      200
#define NB      4
#define NT      512
#define NCH     128

struct Params {
  const float *yin;
  const int   *mg;
  const float *Wdm1,*bdm1,*bdm2;
  const float *Wpr1,*bpr1,*Wpr2,*bpr2,*Wpm,*bpm,*Wps,*bps;
  const float *Wd1,*bd1,*Wd2,*bd2,*Wdx,*bdx,*Wds,*bds;
  const float *bih_mic,*bhh_mic,*bih_mac,*bhh_mac;
  const float *eps_g,*eps_z,*eps_x;
  const int   *burn;
  const float *WihTmic,*WhhTmic,*WihTmac,*WhhTmac,*Wdm2p;
  float *hmac_ws,*hmic_ws;
  int   *cidx;          // [2][NCH][NA][NB]
  float *ret,*goals;
};

__device__ __forceinline__ float sigm(float x){ return 1.f/(1.f+expf(-x)); }
__device__ __forceinline__ float softplusf(float x){ return log1pf(expf(-fabsf(x))) + fmaxf(x,0.f); }

// acc[c][j] += sum over this kseg's k (8-way split) of act[j*astride+k]*W[k*N+o+c]
template<int NBv>
__device__ __forceinline__ void mv8(const float* __restrict__ W, int N, int K,
                                    const float* __restrict__ act, int astride,
                                    int o, int kseg, float acc[4][NBv])
{
  const int Q = K >> 2;
  const int qpt = (Q + 7) >> 3;
  int q0 = kseg * qpt;
  int q1 = (Q < q0 + qpt) ? Q : (q0 + qpt);
  for (int q = q0; q < q1; ++q) {
    const float* wr = W + (size_t)(4*q)*N + o;
    const float4 w0 = *(const float4*)(wr);
    const float4 w1 = *(const float4*)(wr + N);
    const float4 w2 = *(const float4*)(wr + 2*N);
    const float4 w3 = *(const float4*)(wr + 3*N);
    #pragma unroll
    for (int j = 0; j < NBv; ++j) {
      const float4 av = *(const float4*)(act + j*astride + 4*q);
      acc[0][j] = fmaf(av.x, w0.x, acc[0][j]);
      acc[1][j] = fmaf(av.x, w0.y, acc[1][j]);
      acc[2][j] = fmaf(av.x, w0.z, acc[2][j]);
      acc[3][j] = fmaf(av.x, w0.w, acc[3][j]);
      acc[0][j] = fmaf(av.y, w1.x, acc[0][j]);
      acc[1][j] = fmaf(av.y, w1.y, acc[1][j]);
      acc[2][j] = fmaf(av.y, w1.z, acc[2][j]);
      acc[3][j] = fmaf(av.y, w1.w, acc[3][j]);
      acc[0][j] = fmaf(av.z, w2.x, acc[0][j]);
      acc[1][j] = fmaf(av.z, w2.y, acc[1][j]);
      acc[2][j] = fmaf(av.z, w2.z, acc[2][j]);
      acc[3][j] = fmaf(av.z, w2.w, acc[3][j]);
      acc[0][j] = fmaf(av.w, w3.x, acc[0][j]);
      acc[1][j] = fmaf(av.w, w3.y, acc[1][j]);
      acc[2][j] = fmaf(av.w, w3.z, acc[2][j]);
      acc[3][j] = fmaf(av.w, w3.w, acc[3][j]);
    }
  }
  if (kseg == 7) {                     // K%4 tail
    for (int k = Q*4; k < K; ++k) {
      const float4 w = *(const float4*)(W + (size_t)k*N + o);
      #pragma unroll
      for (int j = 0; j < NBv; ++j) {
        const float a = act[j*astride + k];
        acc[0][j] = fmaf(a, w.x, acc[0][j]);
        acc[1][j] = fmaf(a, w.y, acc[1][j]);
        acc[2][j] = fmaf(a, w.z, acc[2][j]);
        acc[3][j] = fmaf(a, w.w, acc[3][j]);
      }
    }
  }
}

template<int NBv>
__device__ __forceinline__ void qreduce8(float acc[4][NBv]) {
  #pragma unroll
  for (int c = 0; c < 4; ++c)
    #pragma unroll
    for (int j = 0; j < NBv; ++j) {
      float v = acc[c][j];
      v += __shfl_xor(v, 1);
      v += __shfl_xor(v, 2);
      v += __shfl_xor(v, 4);
      acc[c][j] = v;
    }
}

__global__ void prep_kernel(const float* __restrict__ Whh_mac, const float* __restrict__ Whh_mic,
                            const float* __restrict__ Wih_mic, const float* __restrict__ Wih_mac,
                            const float* __restrict__ Wdm2,
                            float* __restrict__ WhhTmac, float* __restrict__ WhhTmic,
                            float* __restrict__ WihTmic, float* __restrict__ WihTmac,
                            float* __restrict__ Wdm2p)
{
  int i = blockIdx.x * 256 + threadIdx.x;
  if (i < 120000) {                     // (600,200)->(200,600)
    int k = i / 600, g = i % 600;
    WhhTmac[i] = Whh_mac[g*200 + k];
  } else if (i < 720000) {              // (A,600,200)->(A,200,600)
    int j = i - 120000;
    int a = j / 120000, r = j % 120000;
    int k = r / 600, g = r % 600;
    WhhTmic[j] = Whh_mic[a*120000 + g*200 + k];
  } else if (i < 774000) {              // (A,600,18)->(A,18,600)
    int j = i - 720000;
    int a = j / 10800, r = j % 10800;
    int k = r / 600, g = r % 600;
    WihTmic[j] = Wih_mic[a*10800 + g*18 + k];
  } else if (i < 1044000) {             // (600,450)->(450,600)
    int j = i - 774000;
    int k = j / 600, g = j % 600;
    WihTmac[j] = Wih_mac[g*450 + k];
  } else if (i < 1140000) {             // (A,200,90)->(A,200,96) pad
    int j = i - 1044000;
    int a = j / 19200, r = j % 19200;
    int k = r / 96, o = r % 96;
    Wdm2p[j] = (o < 90) ? Wdm2[(a*200 + k)*90 + o] : 0.f;
  }
}

__global__ __launch_bounds__(NT, 4) void step_kernel(Params p, int t)
{
  __shared__ __align__(16) float sHmac[NB][208];
  __shared__ __align__(16) float sHmic[NB][208];
  __shared__ __align__(16) float sXC[NB][20];
  __shared__ __align__(16) float sZ[NB][16];
  __shared__ float sRedM[NB][2][8];
  __shared__ float sRedS[NB][2][8];
  __shared__ __align__(16) union ScratchU {
    float gs[NB][400];   // GRU gates: [0,200)=r-pre (overwritten by n-comb), [200,400)=z-pre
    struct { float b1[NB][208]; float b2[NB][208]; float lg[NB][96]; float y[NB][12]; } m;
  } U;
  __shared__ int sIdxP[NA][NB];
  __shared__ int sMid[NB];

  const int tid = threadIdx.x;
  const int bid = blockIdx.x;
  const int X = bid & 7, slot = bid >> 3;     // 640 = 8 XCDs x 80
  const int jj = X * 80 + slot;
  const int a  = jj >> 7;                     // 128 chunks per agent
  const int c  = jj & 127;
  const int b0 = c * NB;
  const int burn = p.burn[0];
  const int og = tid >> 3;                    // 64 output-quad groups
  const int kseg = tid & 7;                   // 8-way K split

  // ---- P0: h states, prev idx ----
  if (t == 0) {
    for (int u = tid; u < NB*HM; u += NT) {
      int j = u / HM, k = u % HM;
      sHmac[j][k] = 0.f; sHmic[j][k] = 0.f;
    }
    if (tid < NB*XDIM) {                 // ret[0] = y[0] (own dims)
      int j = tid >> 1, o = tid & 1;
      p.ret[(b0+j)*YDIM + a*XDIM + o] = p.yin[(b0+j)*YDIM + a*XDIM + o];
    }
  } else {
    for (int u = tid; u < NB*HM; u += NT) {
      int j = u / HM, k = u % HM;
      size_t soff = ((size_t)a*BATCH + b0 + j)*HM + k;
      sHmac[j][k] = p.hmac_ws[soff];
      sHmic[j][k] = p.hmic_ws[soff];
    }
    if (tid < NA*NB) {
      int a2 = tid >> 2, j = tid & 3;
      sIdxP[a2][j] = p.cidx[((t-1)&1)*(NCH*NA*NB) + c*(NA*NB) + a2*NB + j];
    }
  }
  __syncthreads();

  // ---- P1: h_mac GRU (deferred: uses idx from step t-1), replicated ----
  if (t > 0) {
    // pass A: rows [0,400): gs = (i+bi) + (h+bh)
    #pragma unroll 1
    for (int pass = 0; pass < 2; ++pass) {
      int gq = og + pass*64;
      if (gq < 100) {
        int g = gq*4;
        float aI[4][NB], aH[4][NB];
        #pragma unroll
        for (int cc = 0; cc < 4; ++cc)
          #pragma unroll
          for (int j = 0; j < NB; ++j) { aI[cc][j] = 0.f; aH[cc][j] = 0.f; }
        if (kseg < NA) {
          int a2 = kseg;
          #pragma unroll
          for (int j = 0; j < NB; ++j) {
            int r = sIdxP[a2][j];
            if (r >= 0) {
              const float4 w = *(const float4*)(p.WihTmac + (size_t)(a2*MDIM + r)*600 + g);
              aI[0][j] += w.x; aI[1][j] += w.y; aI[2][j] += w.z; aI[3][j] += w.w;
            }
          }
        }
        mv8<NB>(p.WhhTmac, 600, HM, &sHmac[0][0], 208, g, kseg, aH);
        qreduce8<NB>(aI);
        qreduce8<NB>(aH);
        const float4 bi = *(const float4*)(p.bih_mac + g);
        const float4 bh = *(const float4*)(p.bhh_mac + g);
        #pragma unroll
        for (int j = 0; j < NB; ++j) {
          if (kseg == 2*j) {
            *(float4*)&U.gs[j][g] = make_float4(aI[0][j]+bi.x+aH[0][j]+bh.x,
                                                aI[1][j]+bi.y+aH[1][j]+bh.y,
                                                aI[2][j]+bi.z+aH[2][j]+bh.z,
                                                aI[3][j]+bi.w+aH[3][j]+bh.w);
          }
        }
      }
    }
    // pass B: rows [400,600): nc = in + sigm(r)*hn, overwrites r slot (same lane)
    if (og < 50) {
      int g = 400 + og*4, k4 = og*4;
      float aI[4][NB], aH[4][NB];
      #pragma unroll
      for (int cc = 0; cc < 4; ++cc)
        #pragma unroll
        for (int j = 0; j < NB; ++j) { aI[cc][j] = 0.f; aH[cc][j] = 0.f; }
      if (kseg < NA) {
        int a2 = kseg;
        #pragma unroll
        for (int j = 0; j < NB; ++j) {
          int r = sIdxP[a2][j];
          if (r >= 0) {
            const float4 w = *(const float4*)(p.WihTmac + (size_t)(a2*MDIM + r)*600 + g);
            aI[0][j] += w.x; aI[1][j] += w.y; aI[2][j] += w.z; aI[3][j] += w.w;
          }
        }
      }
      mv8<NB>(p.WhhTmac, 600, HM, &sHmac[0][0], 208, g, kseg, aH);
      qreduce8<NB>(aI);
      qreduce8<NB>(aH);
      const float4 bi = *(const float4*)(p.bih_mac + g);
      const float4 bh = *(const float4*)(p.bhh_mac + g);
      #pragma unroll
      for (int j = 0; j < NB; ++j) {
        if (kseg == 2*j) {
          const float4 r4 = *(const float4*)&U.gs[j][k4];
          *(float4*)&U.gs[j][k4] = make_float4(
            aI[0][j]+bi.x + sigm(r4.x)*(aH[0][j]+bh.x),
            aI[1][j]+bi.y + sigm(r4.y)*(aH[1][j]+bh.y),
            aI[2][j]+bi.z + sigm(r4.z)*(aH[2][j]+bh.z),
            aI[3][j]+bi.w + sigm(r4.w)*(aH[3][j]+bh.w));
        }
      }
    }
    __syncthreads();
    for (int u = tid; u < NB*HM; u += NT) {
      int j = u / HM, k = u % HM;
      float zg = sigm(U.gs[j][200+k]);
      sHmac[j][k] = (1.f - zg)*tanhf(U.gs[j][k]) + zg*sHmac[j][k];
    }
    __syncthreads();
  }

  // ---- y_t ----
  for (int u = tid; u < NB*YDIM; u += NT) {
    int j = u / YDIM, k = u % YDIM;
    U.m.y[j][k] = (t == 0) ? p.yin[(b0+j)*YDIM + k]
                           : p.ret[(size_t)t*BATCH*YDIM + (b0+j)*YDIM + k];
  }
  __syncthreads();

  // ---- P2: hdm = relu([y,hmac]@Wdm1); logits = hdm@Wdm2 ----
  if (og < 50) {
    int o = og*4;
    float acc[4][NB];
    #pragma unroll
    for (int cc = 0; cc < 4; ++cc)
      #pragma unroll
      for (int j = 0; j < NB; ++j) acc[cc][j] = 0.f;
    const float* W = p.Wdm1 + (size_t)a*(YDIM+HM)*HD;
    mv8<NB>(W, HD, YDIM, &U.m.y[0][0], 12, o, kseg, acc);
    mv8<NB>(W + (size_t)YDIM*HD, HD, HM, &sHmac[0][0], 208, o, kseg, acc);
    qreduce8<NB>(acc);
    const float4 bv = *(const float4*)(p.bdm1 + a*HD + o);
    #pragma unroll
    for (int j = 0; j < NB; ++j) {
      if (kseg == 2*j) {
        *(float4*)&U.m.b1[j][o] = make_float4(
          fmaxf(acc[0][j]+bv.x, 0.f), fmaxf(acc[1][j]+bv.y, 0.f),
          fmaxf(acc[2][j]+bv.z, 0.f), fmaxf(acc[3][j]+bv.w, 0.f));
      }
    }
  }
  __syncthreads();
  if (og < 24) {
    int o = og*4;
    float acc[4][NB];
    #pragma unroll
    for (int cc = 0; cc < 4; ++cc)
      #pragma unroll
      for (int j = 0; j < NB; ++j) acc[cc][j] = 0.f;
    mv8<NB>(p.Wdm2p + (size_t)a*HD*96, 96, HD, &U.m.b1[0][0], 208, o, kseg, acc);
    qreduce8<NB>(acc);
    float b0v = (o+0 < MDIM) ? p.bdm2[a*MDIM + o+0] : 0.f;
    float b1v = (o+1 < MDIM) ? p.bdm2[a*MDIM + o+1] : 0.f;
    float b2v = (o+2 < MDIM) ? p.bdm2[a*MDIM + o+2] : 0.f;
    float b3v = (o+3 < MDIM) ? p.bdm2[a*MDIM + o+3] : 0.f;
    #pragma unroll
    for (int j = 0; j < NB; ++j) {
      if (kseg == 2*j) {
        *(float4*)&U.m.lg[j][o] = make_float4(acc[0][j]+b0v, acc[1][j]+b1v,
                                              acc[2][j]+b2v, acc[3][j]+b3v);
      }
    }
  }
  __syncthreads();
  if (tid < NB*MDIM) {
    int j = tid / MDIM, cc = tid % MDIM;
    U.m.lg[j][cc] += p.eps_g[(((size_t)t*NA + a)*BATCH + b0 + j)*MDIM + cc];
  }
  __syncthreads();
  if (tid < 32) {                      // parallel argmax: j = tid>>3, s = tid&7
    int j = tid >> 3, s = tid & 7;
    float best = -3.4e38f; int bi2 = 0;
    for (int cc = s; cc < MDIM; cc += 8) {
      float v = U.m.lg[j][cc];
      if (v > best) { best = v; bi2 = cc; }
    }
    #pragma unroll
    for (int d = 1; d < 8; d <<= 1) {
      float ob = __shfl_xor(best, d); int oi = __shfl_xor(bi2, d);
      if (ob > best || (ob == best && oi < bi2)) { best = ob; bi2 = oi; }
    }
    if (s == 0) {
      int curr = p.mg[(size_t)t*BATCH*NA + a];
      bool sf = (curr == -1) || ((t >= burn) && (burn > 0));
      int mi = sf ? bi2 : ((b0 + j) == 0 ? curr : -1);
      sMid[j] = mi;
      float gv = (float)(mi < 0 ? 0 : mi);
      p.goals[(size_t)t*BATCH*NA + (b0+j)*NA + a] = gv;
      if (t == T_STEPS-1) p.goals[(size_t)T_STEPS*BATCH*NA + (b0+j)*NA + a] = gv;
      p.cidx[(t&1)*(NCH*NA*NB) + c*(NA*NB) + a*NB + j] = mi;
    }
  }
  __syncthreads();

  // ---- P3: hp = relu(relu([m,hmic]@Wpr1)@Wpr2); z ----
  if (og < 50) {
    int o = og*4;
    float acc[4][NB];
    #pragma unroll
    for (int cc = 0; cc < 4; ++cc)
      #pragma unroll
      for (int j = 0; j < NB; ++j) acc[cc][j] = 0.f;
    const float* W = p.Wpr1 + (size_t)a*(MDIM+HM)*HD;
    #pragma unroll
    for (int j = 0; j < NB; ++j) {
      if (kseg == j) {                 // one-hot gather on lanes 0..3
        int mi = sMid[j];
        if (mi >= 0) {
          const float4 w = *(const float4*)(W + (size_t)mi*HD + o);
          acc[0][j] += w.x; acc[1][j] += w.y; acc[2][j] += w.z; acc[3][j] += w.w;
        }
      }
    }
    mv8<NB>(W + (size_t)MDIM*HD, HD, HM, &sHmic[0][0], 208, o, kseg, acc);
    qreduce8<NB>(acc);
    const float4 bv = *(const float4*)(p.bpr1 + a*HD + o);
    #pragma unroll
    for (int j = 0; j < NB; ++j) {
      if (kseg == 2*j) {
        *(float4*)&U.m.b2[j][o] = make_float4(
          fmaxf(acc[0][j]+bv.x, 0.f), fmaxf(acc[1][j]+bv.y, 0.f),
          fmaxf(acc[2][j]+bv.z, 0.f), fmaxf(acc[3][j]+bv.w, 0.f));
      }
    }
  }
  __syncthreads();
  if (og < 50) {
    int o = og*4;
    float acc[4][NB];
    #pragma unroll
    for (int cc = 0; cc < 4; ++cc)
      #pragma unroll
      for (int j = 0; j < NB; ++j) acc[cc][j] = 0.f;
    mv8<NB>(p.Wpr2 + (size_t)a*HD*HD, HD, HD, &U.m.b2[0][0], 208, o, kseg, acc);
    qreduce8<NB>(acc);
    const float4 bv = *(const float4*)(p.bpr2 + a*HD + o);
    #pragma unroll
    for (int j = 0; j < NB; ++j) {
      if (kseg == 2*j) {
        *(float4*)&U.m.b1[j][o] = make_float4(
          fmaxf(acc[0][j]+bv.x, 0.f), fmaxf(acc[1][j]+bv.y, 0.f),
          fmaxf(acc[2][j]+bv.z, 0.f), fmaxf(acc[3][j]+bv.w, 0.f));
      }
    }
  }
  __syncthreads();
  {                                    // z-head: j=tid>>7, o=(tid>>3)&15, s=tid&7
    int j = tid >> 7, o = (tid >> 3) & 15, s = tid & 7;
    float am = 0.f, as = 0.f;
    const float* wm  = p.Wpm + (size_t)a*HD*ZDIM + o;
    const float* wsp = p.Wps + (size_t)a*HD*ZDIM + o;
    for (int k = s*25; k < s*25 + 25; ++k) {
      float h = U.m.b1[j][k];
      am = fmaf(h, wm[(size_t)k*ZDIM], am);
      as = fmaf(h, wsp[(size_t)k*ZDIM], as);
    }
    am += __shfl_xor(am, 1); am += __shfl_xor(am, 2); am += __shfl_xor(am, 4);
    as += __shfl_xor(as, 1); as += __shfl_xor(as, 2); as += __shfl_xor(as, 4);
    if (s == 0) {
      am += p.bpm[a*ZDIM + o];
      as += p.bps[a*ZDIM + o];
      float zv = am + softplusf(as) * p.eps_z[(((size_t)t*NA + a)*BATCH + b0 + j)*ZDIM + o];
      sZ[j][o] = zv;
      sXC[j][2+o] = zv;
    }
  }
  __syncthreads();

  // ---- P4: hd = relu(relu([y,m,z,hmic]@Wd1)@Wd2); x heads ----
  if (og < 50) {
    int o = og*4;
    float acc[4][NB];
    #pragma unroll
    for (int cc = 0; cc < 4; ++cc)
      #pragma unroll
      for (int j = 0; j < NB; ++j) acc[cc][j] = 0.f;
    const float* W = p.Wd1 + (size_t)a*(YDIM+MDIM+ZDIM+HM)*HD;
    #pragma unroll
    for (int j = 0; j < NB; ++j) {
      if (kseg == j) {
        int mi = sMid[j];
        if (mi >= 0) {
          const float4 w = *(const float4*)(W + (size_t)(YDIM+mi)*HD + o);
          acc[0][j] += w.x; acc[1][j] += w.y; acc[2][j] += w.z; acc[3][j] += w.w;
        }
      }
    }
    mv8<NB>(W, HD, YDIM, &U.m.y[0][0], 12, o, kseg, acc);
    mv8<NB>(W + (size_t)(YDIM+MDIM)*HD, HD, ZDIM, &sZ[0][0], 16, o, kseg, acc);
    mv8<NB>(W + (size_t)(YDIM+MDIM+ZDIM)*HD, HD, HM, &sHmic[0][0], 208, o, kseg, acc);
    qreduce8<NB>(acc);
    const float4 bv = *(const float4*)(p.bd1 + a*HD + o);
    #pragma unroll
    for (int j = 0; j < NB; ++j) {
      if (kseg == 2*j) {
        *(float4*)&U.m.b2[j][o] = make_float4(
          fmaxf(acc[0][j]+bv.x, 0.f), fmaxf(acc[1][j]+bv.y, 0.f),
          fmaxf(acc[2][j]+bv.z, 0.f), fmaxf(acc[3][j]+bv.w, 0.f));
      }
    }
  }
  __syncthreads();
  if (og < 50) {
    int o = og*4;
    float acc[4][NB];
    #pragma unroll
    for (int cc = 0; cc < 4; ++cc)
      #pragma unroll
      for (int j = 0; j < NB; ++j) acc[cc][j] = 0.f;
    mv8<NB>(p.Wd2 + (size_t)a*HD*HD, HD, HD, &U.m.b2[0][0], 208, o, kseg, acc);
    qreduce8<NB>(acc);
    const float4 bv = *(const float4*)(p.bd2 + a*HD + o);
    #pragma unroll
    for (int j = 0; j < NB; ++j) {
      if (kseg == 2*j) {
        *(float4*)&U.m.b1[j][o] = make_float4(
          fmaxf(acc[0][j]+bv.x, 0.f), fmaxf(acc[1][j]+bv.y, 0.f),
          fmaxf(acc[2][j]+bv.z, 0.f), fmaxf(acc[3][j]+bv.w, 0.f));
      }
    }
  }
  __syncthreads();
  if (tid < 64) {                      // x-heads: j=tid>>4, o=(tid>>3)&1, seg=tid&7
    int j = tid >> 4, o = (tid >> 3) & 1, seg = tid & 7;
    float am = 0.f, as = 0.f;
    const float* wx  = p.Wdx + (size_t)a*HD*XDIM + o;
    const float* wsd = p.Wds + (size_t)a*HD*XDIM + o;
    for (int k = seg*25; k < seg*25 + 25; ++k) {
      float h = U.m.b1[j][k];
      am = fmaf(h, wx[(size_t)k*XDIM], am);
      as = fmaf(h, wsd[(size_t)k*XDIM], as);
    }
    sRedM[j][o][seg] = am; sRedS[j][o][seg] = as;
  }
  __syncthreads();
  if (tid < NB*XDIM) {
    int j = tid >> 1, o = tid & 1;
    float am = p.bdx[a*XDIM + o], as = p.bds[a*XDIM + o];
    for (int s2 = 0; s2 < 8; ++s2) { am += sRedM[j][o][s2]; as += sRedS[j][o][s2]; }
    float xs = am + softplusf(as) * p.eps_x[(((size_t)t*NA + a)*BATCH + b0 + j)*XDIM + o];
    float xt = p.yin[((size_t)(t+1))*BATCH*YDIM + (b0+j)*YDIM + a*XDIM + o];
    float xv = (t < burn) ? xt : xs;
    p.ret[((size_t)(t+1))*BATCH*YDIM + (b0+j)*YDIM + a*XDIM + o] = xv;
    sXC[j][o] = xv;
  }
  __syncthreads();

  // ---- P5: h_mic GRU ----
  #pragma unroll 1
  for (int pass = 0; pass < 2; ++pass) {
    int gq = og + pass*64;
    if (gq < 100) {
      int g = gq*4;
      float aI[4][NB], aH[4][NB];
      #pragma unroll
      for (int cc = 0; cc < 4; ++cc)
        #pragma unroll
        for (int j = 0; j < NB; ++j) { aI[cc][j] = 0.f; aH[cc][j] = 0.f; }
      mv8<NB>(p.WihTmic + (size_t)a*18*600, 600, 18, &sXC[0][0], 20, g, kseg, aI);
      mv8<NB>(p.WhhTmic + (size_t)a*HM*600, 600, HM, &sHmic[0][0], 208, g, kseg, aH);
      qreduce8<NB>(aI);
      qreduce8<NB>(aH);
      const float4 bi = *(const float4*)(p.bih_mic + a*600 + g);
      const float4 bh = *(const float4*)(p.bhh_mic + a*600 + g);
      #pragma unroll
      for (int j = 0; j < NB; ++j) {
        if (kseg == 2*j) {
          *(float4*)&U.gs[j][g] = make_float4(aI[0][j]+bi.x+aH[0][j]+bh.x,
                                              aI[1][j]+bi.y+aH[1][j]+bh.y,
                                              aI[2][j]+bi.z+aH[2][j]+bh.z,
                                              aI[3][j]+bi.w+aH[3][j]+bh.w);
        }
      }
    }
  }
  if (og < 50) {
    int g = 400 + og*4, k4 = og*4;
    float aI[4][NB], aH[4][NB];
    #pragma unroll
    for (int cc = 0; cc < 4; ++cc)
      #pragma unroll
      for (int j = 0; j < NB; ++j) { aI[cc][j] = 0.f; aH[cc][j] = 0.f; }
    mv8<NB>(p.WihTmic + (size_t)a*18*600, 600, 18, &sXC[0][0], 20, g, kseg, aI);
    mv8<NB>(p.WhhTmic + (size_t)a*HM*600, 600, HM, &sHmic[0][0], 208, g, kseg, aH);
    qreduce8<NB>(aI);
    qreduce8<NB>(aH);
    const float4 bi = *(const float4*)(p.bih_mic + a*600 + g);
    const float4 bh = *(const float4*)(p.bhh_mic + a*600 + g);
    #pragma unroll
    for (int j = 0; j < NB; ++j) {
      if (kseg == 2*j) {
        const float4 r4 = *(const float4*)&U.gs[j][k4];
        *(float4*)&U.gs[j][k4] = make_float4(
          aI[0][j]+bi.x + sigm(r4.x)*(aH[0][j]+bh.x),
          aI[1][j]+bi.y + sigm(r4.y)*(aH[1][j]+bh.y),
          aI[2][j]+bi.z + sigm(r4.z)*(aH[2][j]+bh.z),
          aI[3][j]+bi.w + sigm(r4.w)*(aH[3][j]+bh.w));
      }
    }
  }
  __syncthreads();
  for (int u = tid; u < NB*HM; u += NT) {
    int j = u / HM, k = u % HM;
    float zg = sigm(U.gs[j][200+k]);
    float nh = (1.f - zg)*tanhf(U.gs[j][k]) + zg*sHmic[j][k];
    size_t soff = ((size_t)a*BATCH + b0 + j)*HM + k;
    p.hmic_ws[soff] = nh;
    p.hmac_ws[soff] = sHmac[j][k];
  }
}

extern "C" void kernel_launch(void* const* d_in, const int* in_sizes, int n_in,
                              void* d_out, int out_size, void* d_ws, size_t ws_size,
                              hipStream_t stream) {
  (void)in_sizes; (void)n_in; (void)out_size; (void)ws_size;
  Params p;
  p.yin   = (const float*)d_in[0];
  p.mg    = (const int*)  d_in[1];
  p.Wdm1  = (const float*)d_in[2];  p.bdm1 = (const float*)d_in[3];
  const float* Wdm2 = (const float*)d_in[4];
  p.bdm2  = (const float*)d_in[5];
  p.Wpr1  = (const float*)d_in[6];  p.bpr1 = (const float*)d_in[7];
  p.Wpr2  = (const float*)d_in[8];  p.bpr2 = (const float*)d_in[9];
  p.Wpm   = (const float*)d_in[10]; p.bpm  = (const float*)d_in[11];
  p.Wps   = (const float*)d_in[12]; p.bps  = (const float*)d_in[13];
  p.Wd1   = (const float*)d_in[14]; p.bd1  = (const float*)d_in[15];
  p.Wd2   = (const float*)d_in[16]; p.bd2  = (const float*)d_in[17];
  p.Wdx   = (const float*)d_in[18]; p.bdx  = (const float*)d_in[19];
  p.Wds   = (const float*)d_in[20]; p.bds  = (const float*)d_in[21];
  const float* Wih_mic = (const float*)d_in[22];
  const float* Whh_mic = (const float*)d_in[23];
  p.bih_mic = (const float*)d_in[24]; p.bhh_mic = (const float*)d_in[25];
  const float* Wih_mac = (const float*)d_in[26];
  const float* Whh_mac = (const float*)d_in[27];
  p.bih_mac = (const float*)d_in[28]; p.bhh_mac = (const float*)d_in[29];
  p.eps_g = (const float*)d_in[30];
  p.eps_z = (const float*)d_in[31];
  p.eps_x = (const float*)d_in[32];
  p.burn  = (const int*)  d_in[33];

  float* ws = (float*)d_ws;
  float* WhhTmac = ws;                 // 120000
  float* WhhTmic = ws + 120000;        // 600000
  float* WihTmic = ws + 720000;        // 54000
  float* WihTmac = ws + 774000;        // 270000
  float* Wdm2p   = ws + 1044000;       // 96000
  p.hmac_ws = ws + 1140000;            // 512000
  p.hmic_ws = ws + 1652000;            // 512000
  p.cidx = (int*)(ws + 2164000);       // 5120 ints
  p.WhhTmac = WhhTmac; p.WhhTmic = WhhTmic; p.WihTmic = WihTmic; p.WihTmac = WihTmac;
  p.Wdm2p = Wdm2p;

  p.ret   = (float*)d_out;
  p.goals = (float*)d_out + (size_t)(T_STEPS+1)*BATCH*YDIM;

  prep_kernel<<<(1140000 + 255)/256, 256, 0, stream>>>(
      Whh_mac, Whh_mic, Wih_mic, Wih_mac, Wdm2,
      WhhTmac, WhhTmic, WihTmic, WihTmac, Wdm2p);

  for (int t = 0; t < T_STEPS; ++t)
    step_kernel<<<NA*NCH, NT, 0, stream>>>(p, t);
}

// Round 9
// 10798.830 us; speedup vs baseline: 1.2357x; 1.2357x over previous
//
#include <hip/hip_runtime.h>

// MACRO_VRNN R9: R8 with the actual bug fixed. R7/R8's goals failure was NOT
// the prefetch UB: the eps_g (gumbel) add used `if (tid < NB*MDIM)` (=360)
// copied from R6 where NT=512; at NT=256 rows j=3 (and part of j=2) got no
// noise -> argmax != ref sampled goal -> goals absmax 89, y unaffected.
// Fix: grid-stride loop. Structure kept from R7: per-step launches, NB=4,
// NT=256, grid=640; mac-GRU de-replicated (shared across agents); NT hints
// on read-only eps streams; defined-value mv4 register prefetch.

#define T_STEPS 63
#define BATCH   512
#define NA      5
#define YDIM    10
#define ZDIM    16
#define XDIM    2
#define HD      200
#define MDIM    90
#define HM      200
#define NB      4
#define NT      256
#define NCH     128

struct Params {
  const float *yin;
  const int   *mg;
  const float *Wdm1,*bdm1,*bdm2;
  const float *Wpr1,*bpr1,*Wpr2,*bpr2,*Wpm,*bpm,*Wps,*bps;
  const float *Wd1,*bd1,*Wd2,*bd2,*Wdx,*bdx,*Wds,*bds;
  const float *bih_mic,*bhh_mic,*bih_mac,*bhh_mac;
  const float *eps_g,*eps_z,*eps_x;
  const int   *burn;
  const float *WihTmic,*WhhTmic,*WihTmac,*WhhTmac,*Wdm2p;
  float *hmac_ws;       // [BATCH][HM]  (shared across agents — one copy)
  float *hmic_ws;       // [A][BATCH][HM]
  int   *cidx;          // [2][NCH][NA][NB]
  float *ret,*goals;
};

__device__ __forceinline__ float sigm(float x){ return 1.f/(1.f+expf(-x)); }
__device__ __forceinline__ float softplusf(float x){ return log1pf(expf(-fabsf(x))) + fmaxf(x,0.f); }

// acc[c][j] += sum over this kseg's k of act[j*astride+k] * W[k*N + o + c]
// Register double-buffer with DEFINED values on every path (no UB).
template<int NBv>
__device__ __forceinline__ void mv4(const float* __restrict__ W, int N, int K,
                                    const float* __restrict__ act, int astride,
                                    int o, int kseg, float acc[4][NBv])
{
  const int Q = K >> 2;
  const int qpt = (Q + 3) >> 2;
  const int q0 = kseg * qpt;
  const int q1 = (Q < q0 + qpt) ? Q : (q0 + qpt);
  if (q0 < q1) {
    const float* wr = W + (size_t)(4*q0)*N + o;
    float4 w0 = *(const float4*)(wr);
    float4 w1 = *(const float4*)(wr + N);
    float4 w2 = *(const float4*)(wr + 2*N);
    float4 w3 = *(const float4*)(wr + 3*N);
    for (int q = q0; q < q1; ++q) {
      float4 n0 = w0, n1 = w1, n2 = w2, n3 = w3;   // defined defaults
      const float* wn = wr + (size_t)4*N;
      if (q + 1 < q1) {                    // issue next-iter loads early
        n0 = *(const float4*)(wn);
        n1 = *(const float4*)(wn + N);
        n2 = *(const float4*)(wn + 2*N);
        n3 = *(const float4*)(wn + 3*N);
      }
      #pragma unroll
      for (int j = 0; j < NBv; ++j) {
        const float4 av = *(const float4*)(act + j*astride + 4*q);
        acc[0][j] = fmaf(av.x, w0.x, acc[0][j]);
        acc[1][j] = fmaf(av.x, w0.y, acc[1][j]);
        acc[2][j] = fmaf(av.x, w0.z, acc[2][j]);
        acc[3][j] = fmaf(av.x, w0.w, acc[3][j]);
        acc[0][j] = fmaf(av.y, w1.x, acc[0][j]);
        acc[1][j] = fmaf(av.y, w1.y, acc[1][j]);
        acc[2][j] = fmaf(av.y, w1.z, acc[2][j]);
        acc[3][j] = fmaf(av.y, w1.w, acc[3][j]);
        acc[0][j] = fmaf(av.z, w2.x, acc[0][j]);
        acc[1][j] = fmaf(av.z, w2.y, acc[1][j]);
        acc[2][j] = fmaf(av.z, w2.z, acc[2][j]);
        acc[3][j] = fmaf(av.z, w2.w, acc[3][j]);
        acc[0][j] = fmaf(av.w, w3.x, acc[0][j]);
        acc[1][j] = fmaf(av.w, w3.y, acc[1][j]);
        acc[2][j] = fmaf(av.w, w3.z, acc[2][j]);
        acc[3][j] = fmaf(av.w, w3.w, acc[3][j]);
      }
      w0 = n0; w1 = n1; w2 = n2; w3 = n3; wr = wn;
    }
  }
  if (kseg == 3) {                         // K%4 tail
    for (int k = Q*4; k < K; ++k) {
      const float4 w = *(const float4*)(W + (size_t)k*N + o);
      #pragma unroll
      for (int j = 0; j < NBv; ++j) {
        const float a = act[j*astride + k];
        acc[0][j] = fmaf(a, w.x, acc[0][j]);
        acc[1][j] = fmaf(a, w.y, acc[1][j]);
        acc[2][j] = fmaf(a, w.z, acc[2][j]);
        acc[3][j] = fmaf(a, w.w, acc[3][j]);
      }
    }
  }
}

template<int NBv>
__device__ __forceinline__ void qreduce(float acc[4][NBv]) {
  #pragma unroll
  for (int c = 0; c < 4; ++c)
    #pragma unroll
    for (int j = 0; j < NBv; ++j) {
      float v = acc[c][j];
      v += __shfl_xor(v, 1);
      v += __shfl_xor(v, 2);
      acc[c][j] = v;
    }
}

__global__ void prep_kernel(const float* __restrict__ Whh_mac, const float* __restrict__ Whh_mic,
                            const float* __restrict__ Wih_mic, const float* __restrict__ Wih_mac,
                            const float* __restrict__ Wdm2,
                            float* __restrict__ WhhTmac, float* __restrict__ WhhTmic,
                            float* __restrict__ WihTmic, float* __restrict__ WihTmac,
                            float* __restrict__ Wdm2p)
{
  int i = blockIdx.x * 256 + threadIdx.x;
  if (i < 120000) {                     // (600,200)->(200,600)
    int k = i / 600, g = i % 600;
    WhhTmac[i] = Whh_mac[g*200 + k];
  } else if (i < 720000) {              // (A,600,200)->(A,200,600)
    int j = i - 120000;
    int a = j / 120000, r = j % 120000;
    int k = r / 600, g = r % 600;
    WhhTmic[j] = Whh_mic[a*120000 + g*200 + k];
  } else if (i < 774000) {              // (A,600,18)->(A,18,600)
    int j = i - 720000;
    int a = j / 10800, r = j % 10800;
    int k = r / 600, g = r % 600;
    WihTmic[j] = Wih_mic[a*10800 + g*18 + k];
  } else if (i < 1044000) {             // (600,450)->(450,600)
    int j = i - 774000;
    int k = j / 600, g = j % 600;
    WihTmac[j] = Wih_mac[g*450 + k];
  } else if (i < 1140000) {             // (A,200,90)->(A,200,96) pad
    int j = i - 1044000;
    int a = j / 19200, r = j % 19200;
    int k = r / 96, o = r % 96;
    Wdm2p[j] = (o < 90) ? Wdm2[(a*200 + k)*90 + o] : 0.f;
  }
}

// h_mac GRU for step t (shared across agents): one block per batch chunk.
// Reads cidx[t-1], updates hmac_ws in place. Launched for t>=1 only.
__global__ __launch_bounds__(NT, 4) void mac_kernel(Params p, int t)
{
  __shared__ __align__(16) float sH[NB][208];
  __shared__ __align__(16) float gs[NB][400];
  __shared__ int sIdx[NA][NB];

  const int tid = threadIdx.x;
  const int c = blockIdx.x;
  const int b0 = c * NB;
  const int og = tid >> 2;
  const int kseg = tid & 3;

  for (int u = tid; u < NB*HM; u += NT) {
    int j = u / HM, k = u % HM;
    sH[j][k] = (t == 1) ? 0.f : p.hmac_ws[(size_t)(b0 + j)*HM + k];
  }
  if (tid < NA*NB) {
    int a2 = tid >> 2, j = tid & 3;
    sIdx[a2][j] = p.cidx[((t-1)&1)*(NCH*NA*NB) + c*(NA*NB) + a2*NB + j];
  }
  __syncthreads();

  // pass A: rows [0,400): gs = (i+bi) + (h+bh)
  #pragma unroll 1
  for (int pass = 0; pass < 2; ++pass) {
    int gq = og + pass*64;
    if (gq < 100) {
      int g = gq*4;
      float aI[4][NB], aH[4][NB];
      #pragma unroll
      for (int cc = 0; cc < 4; ++cc)
        #pragma unroll
        for (int j = 0; j < NB; ++j) { aI[cc][j] = 0.f; aH[cc][j] = 0.f; }
      for (int a2 = kseg; a2 < NA; a2 += 4) {
        #pragma unroll
        for (int j = 0; j < NB; ++j) {
          int r = sIdx[a2][j];
          if (r >= 0) {
            const float4 w = *(const float4*)(p.WihTmac + (size_t)(a2*MDIM + r)*600 + g);
            aI[0][j] += w.x; aI[1][j] += w.y; aI[2][j] += w.z; aI[3][j] += w.w;
          }
        }
      }
      mv4<NB>(p.WhhTmac, 600, HM, &sH[0][0], 208, g, kseg, aH);
      qreduce<NB>(aI);
      qreduce<NB>(aH);
      const float4 bi = *(const float4*)(p.bih_mac + g);
      const float4 bh = *(const float4*)(p.bhh_mac + g);
      #pragma unroll
      for (int j = 0; j < NB; ++j) {
        if (j == kseg) {
          *(float4*)&gs[j][g] = make_float4(aI[0][j]+bi.x+aH[0][j]+bh.x,
                                            aI[1][j]+bi.y+aH[1][j]+bh.y,
                                            aI[2][j]+bi.z+aH[2][j]+bh.z,
                                            aI[3][j]+bi.w+aH[3][j]+bh.w);
        }
      }
    }
  }
  // pass B: rows [400,600): nc = in + sigm(r)*hn, overwrites r slot (same lane)
  if (og < 50) {
    int g = 400 + og*4, k4 = og*4;
    float aI[4][NB], aH[4][NB];
    #pragma unroll
    for (int cc = 0; cc < 4; ++cc)
      #pragma unroll
      for (int j = 0; j < NB; ++j) { aI[cc][j] = 0.f; aH[cc][j] = 0.f; }
    for (int a2 = kseg; a2 < NA; a2 += 4) {
      #pragma unroll
      for (int j = 0; j < NB; ++j) {
        int r = sIdx[a2][j];
        if (r >= 0) {
          const float4 w = *(const float4*)(p.WihTmac + (size_t)(a2*MDIM + r)*600 + g);
          aI[0][j] += w.x; aI[1][j] += w.y; aI[2][j] += w.z; aI[3][j] += w.w;
        }
      }
    }
    mv4<NB>(p.WhhTmac, 600, HM, &sH[0][0], 208, g, kseg, aH);
    qreduce<NB>(aI);
    qreduce<NB>(aH);
    const float4 bi = *(const float4*)(p.bih_mac + g);
    const float4 bh = *(const float4*)(p.bhh_mac + g);
    #pragma unroll
    for (int j = 0; j < NB; ++j) {
      if (j == kseg) {
        const float4 r4 = *(const float4*)&gs[j][k4];
        *(float4*)&gs[j][k4] = make_float4(
          aI[0][j]+bi.x + sigm(r4.x)*(aH[0][j]+bh.x),
          aI[1][j]+bi.y + sigm(r4.y)*(aH[1][j]+bh.y),
          aI[2][j]+bi.z + sigm(r4.z)*(aH[2][j]+bh.z),
          aI[3][j]+bi.w + sigm(r4.w)*(aH[3][j]+bh.w));
      }
    }
  }
  __syncthreads();
  for (int u = tid; u < NB*HM; u += NT) {
    int j = u / HM, k = u % HM;
    float zg = sigm(gs[j][200+k]);
    p.hmac_ws[(size_t)(b0+j)*HM + k] = (1.f - zg)*tanhf(gs[j][k]) + zg*sH[j][k];
  }
}

__global__ __launch_bounds__(NT, 4) void step_kernel(Params p, int t)
{
  __shared__ __align__(16) float sHmac[NB][208];
  __shared__ __align__(16) float sHmic[NB][208];
  __shared__ __align__(16) float sXC[NB][20];
  __shared__ __align__(16) float sZ[NB][16];
  __shared__ float sRedM[NB][2][8];
  __shared__ float sRedS[NB][2][8];
  __shared__ __align__(16) union ScratchU {
    float gs[NB][400];
    struct { float b1[NB][208]; float b2[NB][208]; float lg[NB][96]; float y[NB][12]; } m;
  } U;
  __shared__ int sMid[NB];

  const int tid = threadIdx.x;
  const int bid = blockIdx.x;
  const int X = bid & 7, slot = bid >> 3;     // 640 = 8 XCDs x 80; agent-contig
  const int jj = X * 80 + slot;
  const int a  = jj >> 7;
  const int c  = jj & 127;
  const int b0 = c * NB;
  const int burn = p.burn[0];
  const int og = tid >> 2;
  const int kseg = tid & 3;

  // ---- P0: states (hmac produced by mac_kernel) ----
  if (t == 0) {
    for (int u = tid; u < NB*HM; u += NT) {
      int j = u / HM, k = u % HM;
      sHmac[j][k] = 0.f; sHmic[j][k] = 0.f;
    }
    if (tid < NB*XDIM) {                 // ret[0] = y[0] (own dims)
      int j = tid >> 1, o = tid & 1;
      p.ret[(b0+j)*YDIM + a*XDIM + o] = p.yin[(b0+j)*YDIM + a*XDIM + o];
    }
  } else {
    for (int u = tid; u < NB*HM; u += NT) {
      int j = u / HM, k = u % HM;
      sHmac[j][k] = p.hmac_ws[(size_t)(b0 + j)*HM + k];
      sHmic[j][k] = p.hmic_ws[((size_t)a*BATCH + b0 + j)*HM + k];
    }
  }
  __syncthreads();

  // ---- y_t ----
  for (int u = tid; u < NB*YDIM; u += NT) {
    int j = u / YDIM, k = u % YDIM;
    U.m.y[j][k] = (t == 0) ? p.yin[(b0+j)*YDIM + k]
                           : p.ret[(size_t)t*BATCH*YDIM + (b0+j)*YDIM + k];
  }
  __syncthreads();

  // ---- P2: hdm = relu([y,hmac]@Wdm1); logits = hdm@Wdm2 ----
  if (og < 50) {
    int o = og*4;
    float acc[4][NB];
    #pragma unroll
    for (int cc = 0; cc < 4; ++cc)
      #pragma unroll
      for (int j = 0; j < NB; ++j) acc[cc][j] = 0.f;
    const float* W = p.Wdm1 + (size_t)a*(YDIM+HM)*HD;
    mv4<NB>(W, HD, YDIM, &U.m.y[0][0], 12, o, kseg, acc);
    mv4<NB>(W + (size_t)YDIM*HD, HD, HM, &sHmac[0][0], 208, o, kseg, acc);
    qreduce<NB>(acc);
    const float4 bv = *(const float4*)(p.bdm1 + a*HD + o);
    #pragma unroll
    for (int j = 0; j < NB; ++j) {
      if (j == kseg) {
        *(float4*)&U.m.b1[j][o] = make_float4(
          fmaxf(acc[0][j]+bv.x, 0.f), fmaxf(acc[1][j]+bv.y, 0.f),
          fmaxf(acc[2][j]+bv.z, 0.f), fmaxf(acc[3][j]+bv.w, 0.f));
      }
    }
  }
  __syncthreads();
  if (og < 24) {
    int o = og*4;
    float acc[4][NB];
    #pragma unroll
    for (int cc = 0; cc < 4; ++cc)
      #pragma unroll
      for (int j = 0; j < NB; ++j) acc[cc][j] = 0.f;
    mv4<NB>(p.Wdm2p + (size_t)a*HD*96, 96, HD, &U.m.b1[0][0], 208, o, kseg, acc);
    qreduce<NB>(acc);
    float b0v = (o+0 < MDIM) ? p.bdm2[a*MDIM + o+0] : 0.f;
    float b1v = (o+1 < MDIM) ? p.bdm2[a*MDIM + o+1] : 0.f;
    float b2v = (o+2 < MDIM) ? p.bdm2[a*MDIM + o+2] : 0.f;
    float b3v = (o+3 < MDIM) ? p.bdm2[a*MDIM + o+3] : 0.f;
    #pragma unroll
    for (int j = 0; j < NB; ++j) {
      if (j == kseg) {
        *(float4*)&U.m.lg[j][o] = make_float4(acc[0][j]+b0v, acc[1][j]+b1v,
                                              acc[2][j]+b2v, acc[3][j]+b3v);
      }
    }
  }
  __syncthreads();
  // gumbel add — grid-stride loop (NB*MDIM=360 > NT=256; R7/R8's single-shot
  // guard dropped noise for rows j>=2 -> wrong argmaxes. THE R7/R8 BUG.)
  for (int u = tid; u < NB*MDIM; u += NT) {
    int j = u / MDIM, cc = u % MDIM;
    U.m.lg[j][cc] += __builtin_nontemporal_load(
        &p.eps_g[(((size_t)t*NA + a)*BATCH + b0 + j)*MDIM + cc]);
  }
  __syncthreads();
  if (tid < 32) {                      // parallel argmax: j = tid>>3, s = tid&7
    int j = tid >> 3, s = tid & 7;
    float best = -3.4e38f; int bi2 = 0;
    for (int cc = s; cc < MDIM; cc += 8) {
      float v = U.m.lg[j][cc];
      if (v > best) { best = v; bi2 = cc; }
    }
    #pragma unroll
    for (int d = 1; d < 8; d <<= 1) {
      float ob = __shfl_xor(best, d); int oi = __shfl_xor(bi2, d);
      if (ob > best || (ob == best && oi < bi2)) { best = ob; bi2 = oi; }
    }
    if (s == 0) {
      int curr = p.mg[(size_t)t*BATCH*NA + a];
      bool sf = (curr == -1) || ((t >= burn) && (burn > 0));
      int mi = sf ? bi2 : ((b0 + j) == 0 ? curr : -1);
      sMid[j] = mi;
      float gv = (float)(mi < 0 ? 0 : mi);
      p.goals[(size_t)t*BATCH*NA + (b0+j)*NA + a] = gv;
      if (t == T_STEPS-1) p.goals[(size_t)T_STEPS*BATCH*NA + (b0+j)*NA + a] = gv;
      p.cidx[(t&1)*(NCH*NA*NB) + c*(NA*NB) + a*NB + j] = mi;
    }
  }
  __syncthreads();

  // ---- P3: hp = relu(relu([m,hmic]@Wpr1)@Wpr2); z ----
  if (og < 50) {
    int o = og*4;
    float acc[4][NB];
    #pragma unroll
    for (int cc = 0; cc < 4; ++cc)
      #pragma unroll
      for (int j = 0; j < NB; ++j) acc[cc][j] = 0.f;
    const float* W = p.Wpr1 + (size_t)a*(MDIM+HM)*HD;
    #pragma unroll
    for (int j = 0; j < NB; ++j) {
      if (kseg == j) {
        int mi = sMid[j];
        if (mi >= 0) {
          const float4 w = *(const float4*)(W + (size_t)mi*HD + o);
          acc[0][j] += w.x; acc[1][j] += w.y; acc[2][j] += w.z; acc[3][j] += w.w;
        }
      }
    }
    mv4<NB>(W + (size_t)MDIM*HD, HD, HM, &sHmic[0][0], 208, o, kseg, acc);
    qreduce<NB>(acc);
    const float4 bv = *(const float4*)(p.bpr1 + a*HD + o);
    #pragma unroll
    for (int j = 0; j < NB; ++j) {
      if (j == kseg) {
        *(float4*)&U.m.b2[j][o] = make_float4(
          fmaxf(acc[0][j]+bv.x, 0.f), fmaxf(acc[1][j]+bv.y, 0.f),
          fmaxf(acc[2][j]+bv.z, 0.f), fmaxf(acc[3][j]+bv.w, 0.f));
      }
    }
  }
  __syncthreads();
  if (og < 50) {
    int o = og*4;
    float acc[4][NB];
    #pragma unroll
    for (int cc = 0; cc < 4; ++cc)
      #pragma unroll
      for (int j = 0; j < NB; ++j) acc[cc][j] = 0.f;
    mv4<NB>(p.Wpr2 + (size_t)a*HD*HD, HD, HD, &U.m.b2[0][0], 208, o, kseg, acc);
    qreduce<NB>(acc);
    const float4 bv = *(const float4*)(p.bpr2 + a*HD + o);
    #pragma unroll
    for (int j = 0; j < NB; ++j) {
      if (j == kseg) {
        *(float4*)&U.m.b1[j][o] = make_float4(
          fmaxf(acc[0][j]+bv.x, 0.f), fmaxf(acc[1][j]+bv.y, 0.f),
          fmaxf(acc[2][j]+bv.z, 0.f), fmaxf(acc[3][j]+bv.w, 0.f));
      }
    }
  }
  __syncthreads();
  {                                    // z-head: j=tid>>6, o=(tid>>2)&15, s=tid&3
    int j = tid >> 6, o = (tid >> 2) & 15, s = tid & 3;
    float am = 0.f, as = 0.f;
    const float* wm  = p.Wpm + (size_t)a*HD*ZDIM + o;
    const float* wsp = p.Wps + (size_t)a*HD*ZDIM + o;
    for (int k = s*50; k < s*50 + 50; ++k) {
      float h = U.m.b1[j][k];
      am = fmaf(h, wm[(size_t)k*ZDIM], am);
      as = fmaf(h, wsp[(size_t)k*ZDIM], as);
    }
    am += __shfl_xor(am, 1); am += __shfl_xor(am, 2);
    as += __shfl_xor(as, 1); as += __shfl_xor(as, 2);
    if (s == 0) {
      am += p.bpm[a*ZDIM + o];
      as += p.bps[a*ZDIM + o];
      float zv = am + softplusf(as) * __builtin_nontemporal_load(
          &p.eps_z[(((size_t)t*NA + a)*BATCH + b0 + j)*ZDIM + o]);
      sZ[j][o] = zv;
      sXC[j][2+o] = zv;
    }
  }
  __syncthreads();

  // ---- P4: hd = relu(relu([y,m,z,hmic]@Wd1)@Wd2); x heads ----
  if (og < 50) {
    int o = og*4;
    float acc[4][NB];
    #pragma unroll
    for (int cc = 0; cc < 4; ++cc)
      #pragma unroll
      for (int j = 0; j < NB; ++j) acc[cc][j] = 0.f;
    const float* W = p.Wd1 + (size_t)a*(YDIM+MDIM+ZDIM+HM)*HD;
    #pragma unroll
    for (int j = 0; j < NB; ++j) {
      if (kseg == j) {
        int mi = sMid[j];
        if (mi >= 0) {
          const float4 w = *(const float4*)(W + (size_t)(YDIM+mi)*HD + o);
          acc[0][j] += w.x; acc[1][j] += w.y; acc[2][j] += w.z; acc[3][j] += w.w;
        }
      }
    }
    mv4<NB>(W, HD, YDIM, &U.m.y[0][0], 12, o, kseg, acc);
    mv4<NB>(W + (size_t)(YDIM+MDIM)*HD, HD, ZDIM, &sZ[0][0], 16, o, kseg, acc);
    mv4<NB>(W + (size_t)(YDIM+MDIM+ZDIM)*HD, HD, HM, &sHmic[0][0], 208, o, kseg, acc);
    qreduce<NB>(acc);
    const float4 bv = *(const float4*)(p.bd1 + a*HD + o);
    #pragma unroll
    for (int j = 0; j < NB; ++j) {
      if (j == kseg) {
        *(float4*)&U.m.b2[j][o] = make_float4(
          fmaxf(acc[0][j]+bv.x, 0.f), fmaxf(acc[1][j]+bv.y, 0.f),
          fmaxf(acc[2][j]+bv.z, 0.f), fmaxf(acc[3][j]+bv.w, 0.f));
      }
    }
  }
  __syncthreads();
  if (og < 50) {
    int o = og*4;
    float acc[4][NB];
    #pragma unroll
    for (int cc = 0; cc < 4; ++cc)
      #pragma unroll
      for (int j = 0; j < NB; ++j) acc[cc][j] = 0.f;
    mv4<NB>(p.Wd2 + (size_t)a*HD*HD, HD, HD, &U.m.b2[0][0], 208, o, kseg, acc);
    qreduce<NB>(acc);
    const float4 bv = *(const float4*)(p.bd2 + a*HD + o);
    #pragma unroll
    for (int j = 0; j < NB; ++j) {
      if (j == kseg) {
        *(float4*)&U.m.b1[j][o] = make_float4(
          fmaxf(acc[0][j]+bv.x, 0.f), fmaxf(acc[1][j]+bv.y, 0.f),
          fmaxf(acc[2][j]+bv.z, 0.f), fmaxf(acc[3][j]+bv.w, 0.f));
      }
    }
  }
  __syncthreads();
  if (tid < 64) {                      // x-heads: j=tid>>4, o=(tid>>3)&1, seg=tid&7
    int j = tid >> 4, o = (tid >> 3) & 1, seg = tid & 7;
    float am = 0.f, as = 0.f;
    const float* wx  = p.Wdx + (size_t)a*HD*XDIM + o;
    const float* wsd = p.Wds + (size_t)a*HD*XDIM + o;
    for (int k = seg*25; k < seg*25 + 25; ++k) {
      float h = U.m.b1[j][k];
      am = fmaf(h, wx[(size_t)k*XDIM], am);
      as = fmaf(h, wsd[(size_t)k*XDIM], as);
    }
    sRedM[j][o][seg] = am; sRedS[j][o][seg] = as;
  }
  __syncthreads();
  if (tid < NB*XDIM) {
    int j = tid >> 1, o = tid & 1;
    float am = p.bdx[a*XDIM + o], as = p.bds[a*XDIM + o];
    for (int s2 = 0; s2 < 8; ++s2) { am += sRedM[j][o][s2]; as += sRedS[j][o][s2]; }
    float xs = am + softplusf(as) * __builtin_nontemporal_load(
        &p.eps_x[(((size_t)t*NA + a)*BATCH + b0 + j)*XDIM + o]);
    float xt = p.yin[((size_t)(t+1))*BATCH*YDIM + (b0+j)*YDIM + a*XDIM + o];
    float xv = (t < burn) ? xt : xs;
    p.ret[((size_t)(t+1))*BATCH*YDIM + (b0+j)*YDIM + a*XDIM + o] = xv;
    sXC[j][o] = xv;
  }
  __syncthreads();

  // ---- P5: h_mic GRU ----
  #pragma unroll 1
  for (int pass = 0; pass < 2; ++pass) {
    int gq = og + pass*64;
    if (gq < 100) {
      int g = gq*4;
      float aI[4][NB], aH[4][NB];
      #pragma unroll
      for (int cc = 0; cc < 4; ++cc)
        #pragma unroll
        for (int j = 0; j < NB; ++j) { aI[cc][j] = 0.f; aH[cc][j] = 0.f; }
      mv4<NB>(p.WihTmic + (size_t)a*18*600, 600, 18, &sXC[0][0], 20, g, kseg, aI);
      mv4<NB>(p.WhhTmic + (size_t)a*HM*600, 600, HM, &sHmic[0][0], 208, g, kseg, aH);
      qreduce<NB>(aI);
      qreduce<NB>(aH);
      const float4 bi = *(const float4*)(p.bih_mic + a*600 + g);
      const float4 bh = *(const float4*)(p.bhh_mic + a*600 + g);
      #pragma unroll
      for (int j = 0; j < NB; ++j) {
        if (j == kseg) {
          *(float4*)&U.gs[j][g] = make_float4(aI[0][j]+bi.x+aH[0][j]+bh.x,
                                              aI[1][j]+bi.y+aH[1][j]+bh.y,
                                              aI[2][j]+bi.z+aH[2][j]+bh.z,
                                              aI[3][j]+bi.w+aH[3][j]+bh.w);
        }
      }
    }
  }
  if (og < 50) {
    int g = 400 + og*4, k4 = og*4;
    float aI[4][NB], aH[4][NB];
    #pragma unroll
    for (int cc = 0; cc < 4; ++cc)
      #pragma unroll
      for (int j = 0; j < NB; ++j) { aI[cc][j] = 0.f; aH[cc][j] = 0.f; }
    mv4<NB>(p.WihTmic + (size_t)a*18*600, 600, 18, &sXC[0][0], 20, g, kseg, aI);
    mv4<NB>(p.WhhTmic + (size_t)a*HM*600, 600, HM, &sHmic[0][0], 208, g, kseg, aH);
    qreduce<NB>(aI);
    qreduce<NB>(aH);
    const float4 bi = *(const float4*)(p.bih_mic + a*600 + g);
    const float4 bh = *(const float4*)(p.bhh_mic + a*600 + g);
    #pragma unroll
    for (int j = 0; j < NB; ++j) {
      if (j == kseg) {
        const float4 r4 = *(const float4*)&U.gs[j][k4];
        *(float4*)&U.gs[j][k4] = make_float4(
          aI[0][j]+bi.x + sigm(r4.x)*(aH[0][j]+bh.x),
          aI[1][j]+bi.y + sigm(r4.y)*(aH[1][j]+bh.y),
          aI[2][j]+bi.z + sigm(r4.z)*(aH[2][j]+bh.z),
          aI[3][j]+bi.w + sigm(r4.w)*(aH[3][j]+bh.w));
      }
    }
  }
  __syncthreads();
  for (int u = tid; u < NB*HM; u += NT) {
    int j = u / HM, k = u % HM;
    float zg = sigm(U.gs[j][200+k]);
    float nh = (1.f - zg)*tanhf(U.gs[j][k]) + zg*sHmic[j][k];
    p.hmic_ws[((size_t)a*BATCH + b0 + j)*HM + k] = nh;
  }
}

extern "C" void kernel_launch(void* const* d_in, const int* in_sizes, int n_in,
                              void* d_out, int out_size, void* d_ws, size_t ws_size,
                              hipStream_t stream) {
  (void)in_sizes; (void)n_in; (void)out_size; (void)ws_size;
  Params p;
  p.yin   = (const float*)d_in[0];
  p.mg    = (const int*)  d_in[1];
  p.Wdm1  = (const float*)d_in[2];  p.bdm1 = (const float*)d_in[3];
  const float* Wdm2 = (const float*)d_in[4];
  p.bdm2  = (const float*)d_in[5];
  p.Wpr1  = (const float*)d_in[6];  p.bpr1 = (const float*)d_in[7];
  p.Wpr2  = (const float*)d_in[8];  p.bpr2 = (const float*)d_in[9];
  p.Wpm   = (const float*)d_in[10]; p.bpm  = (const float*)d_in[11];
  p.Wps   = (const float*)d_in[12]; p.bps  = (const float*)d_in[13];
  p.Wd1   = (const float*)d_in[14]; p.bd1  = (const float*)d_in[15];
  p.Wd2   = (const float*)d_in[16]; p.bd2  = (const float*)d_in[17];
  p.Wdx   = (const float*)d_in[18]; p.bdx  = (const float*)d_in[19];
  p.Wds   = (const float*)d_in[20]; p.bds  = (const float*)d_in[21];
  const float* Wih_mic = (const float*)d_in[22];
  const float* Whh_mic = (const float*)d_in[23];
  p.bih_mic = (const float*)d_in[24]; p.bhh_mic = (const float*)d_in[25];
  const float* Wih_mac = (const float*)d_in[26];
  const float* Whh_mac = (const float*)d_in[27];
  p.bih_mac = (const float*)d_in[28]; p.bhh_mac = (const float*)d_in[29];
  p.eps_g = (const float*)d_in[30];
  p.eps_z = (const float*)d_in[31];
  p.eps_x = (const float*)d_in[32];
  p.burn  = (const int*)  d_in[33];

  float* ws = (float*)d_ws;
  float* WhhTmac = ws;                 // 120000
  float* WhhTmic = ws + 120000;        // 600000
  float* WihTmic = ws + 720000;        // 54000
  float* WihTmac = ws + 774000;        // 270000
  float* Wdm2p   = ws + 1044000;       // 96000
  p.hmac_ws = ws + 1140000;            // 102400 (shared, one copy)
  p.hmic_ws = ws + 1242400;            // 512000
  p.cidx = (int*)(ws + 1754400);       // 5120 ints
  p.WhhTmac = WhhTmac; p.WhhTmic = WhhTmic; p.WihTmic = WihTmic; p.WihTmac = WihTmac;
  p.Wdm2p = Wdm2p;

  p.ret   = (float*)d_out;
  p.goals = (float*)d_out + (size_t)(T_STEPS+1)*BATCH*YDIM;

  prep_kernel<<<(1140000 + 255)/256, 256, 0, stream>>>(
      Whh_mac, Whh_mic, Wih_mic, Wih_mac, Wdm2,
      WhhTmac, WhhTmic, WihTmic, WihTmac, Wdm2p);

  for (int t = 0; t < T_STEPS; ++t) {
    if (t > 0) mac_kernel<<<NCH, NT, 0, stream>>>(p, t);
    step_kernel<<<NA*NCH, NT, 0, stream>>>(p, t);
  }
}